// Round 4
// baseline (381.516 us; speedup 1.0000x reference)
//
#include <hip/hip_runtime.h>
#include <hip/hip_bf16.h>
#include <stdint.h>

// Problem constants (fixed by setup_inputs)
#define T_   24
#define D_   128
#define H_   96
#define W_   128
#define N_   256
#define KP   49      // 7x7 support points
#define K2   3136    // vol K-dim: 49 k-rows x 64 l-slots (l>=49 zero-padded)
#define H1   384     // MLP hidden
#define OUTC 256     // MLP out
#define MTOT (4 * T_ * N_)   // 24576 rows batched over levels

// padded pyramid geometry (8-px zero border on all sides)
#define PAD  8

typedef __attribute__((ext_vector_type(8))) __bf16 bf16x8;
typedef __attribute__((ext_vector_type(4))) float f32x4;

typedef __attribute__((address_space(3))) unsigned int lds_u32;
typedef const __attribute__((address_space(1))) unsigned int g_u32;
#define GLOAD16(g, l) __builtin_amdgcn_global_load_lds((g_u32*)(g), (lds_u32*)(l), 16, 0, 0)

__device__ inline float bf2f(unsigned short u) {
    union { unsigned int i; float f; } v; v.i = ((unsigned int)u) << 16; return v.f;
}
__device__ inline unsigned short f2bf(float f) {
    union { float f; unsigned int i; } v; v.f = f;
    unsigned int i = v.i;
    return (unsigned short)((i + 0x7FFFu + ((i >> 16) & 1u)) >> 16);  // RNE
}

// ---------------- pad zero: border of each padded level buffer ---------------
__global__ __launch_bounds__(256) void k_padzero(uint4* __restrict__ fm,
                                                 int Hs, int Ws) {
    int PW = Ws + 2 * PAD, PH = Hs + 2 * PAD;
    size_t upf = (size_t)PH * PW * 16;   // uint4 units per frame (128 shorts/px)
    size_t total = upf * T_;
    for (size_t idx = (size_t)blockIdx.x * 256 + threadIdx.x; idx < total;
         idx += (size_t)gridDim.x * 256) {
        size_t p = idx >> 4;
        size_t pf = p % ((size_t)PH * PW);
        int y = (int)(pf / PW), x = (int)(pf % PW);
        if (y < PAD || y >= Hs + PAD || x < PAD || x >= Ws + PAD) {
            uint4 z = {0u, 0u, 0u, 0u};
            fm[idx] = z;
        }
    }
}

// ---------------- weight transpose/convert (one-time per call) ----------------
// w1t layout: [n][k*64 + l], l>=49 zero (matches vol layout)
__global__ __launch_bounds__(256) void k_w1t(const float* __restrict__ w1,
                                             unsigned short* __restrict__ w1t) {
    int idx = blockIdx.x * 256 + threadIdx.x;           // H1*K2
    if (idx >= H1 * K2) return;
    int nn = idx / K2, kk = idx % K2;
    int k = kk >> 6, l = kk & 63;
    float v = (l < KP) ? w1[((size_t)k * KP + l) * H1 + nn] : 0.f;
    w1t[idx] = f2bf(v);
}
__global__ __launch_bounds__(256) void k_w2t(const float* __restrict__ w2,
                                             unsigned short* __restrict__ w2t) {
    int idx = blockIdx.x * 256 + threadIdx.x;           // OUTC*H1
    if (idx >= OUTC * H1) return;
    int j = idx / H1, k = idx % H1;
    w2t[idx] = f2bf(w2[(size_t)k * OUTC + j]);
}

// ---------------- L2 normalize + transpose -> padded (T,H,W,D) bf16 ----------
#define PW0 (W_ + 2 * PAD)
#define FR0 ((size_t)(H_ + 2 * PAD) * PW0 * D_)
__global__ __launch_bounds__(256) void k_normalize(const float* __restrict__ fmaps,
                                                   unsigned short* __restrict__ fm0i) {
    int bid = blockIdx.x;                 // t*H_ + h
    int t = bid / H_, h = bid % H_;
    int tid = threadIdx.x;
    __shared__ float ssum[256];
    __shared__ float rs[W_];
    __shared__ float tile[64 * 129];
    const float* base = fmaps + (size_t)t * D_ * H_ * W_ + (size_t)h * W_;
    {   // sum of squares per w (reads coalesced in w)
        int w = tid & 127, half = tid >> 7;
        float ss = 0.f;
        for (int d = half * 64; d < half * 64 + 64; ++d) {
            float v = base[(size_t)d * (H_ * W_) + w];
            ss += v * v;
        }
        ssum[tid] = ss;
    }
    __syncthreads();
    if (tid < W_) rs[tid] = rsqrtf(fmaxf(ssum[tid] + ssum[tid + 128], 1e-12f));
    __syncthreads();
    unsigned short* orow = fm0i + (size_t)t * FR0 + (size_t)h * (PW0 * D_);
    for (int wt = 0; wt < 2; ++wt) {      // transpose 64-w tiles through LDS
        int wl = tid & 63, dg = tid >> 6;
        int w = wt * 64 + wl;
        float r = rs[w];
        for (int d = dg * 32; d < dg * 32 + 32; ++d)
            tile[wl * 129 + d] = base[(size_t)d * (H_ * W_) + w] * r;
        __syncthreads();
        int d2 = tid & 127, wh = tid >> 7;
        for (int i = 0; i < 32; ++i) {
            int wll = wh * 32 + i;
            orow[(size_t)(wt * 64 + wll) * D_ + d2] = f2bf(tile[wll * 129 + d2]);
        }
        __syncthreads();
    }
}

// ---------------- 2x2 avg pool on padded buffers -----------------------------
__global__ __launch_bounds__(256) void k_pool(const unsigned short* __restrict__ ini,
                                              unsigned short* __restrict__ outi,
                                              int Hs, int Ws) {
    int Ho = Hs >> 1, Wo = Ws >> 1;
    int PWi = Ws + 2 * PAD, PWo = Wo + 2 * PAD;
    size_t FRi = (size_t)(Hs + 2 * PAD) * PWi * D_;
    size_t FRo = (size_t)(Ho + 2 * PAD) * PWo * D_;
    size_t total = (size_t)T_ * Ho * Wo * (D_ / 4);
    size_t idx = (size_t)blockIdx.x * 256 + threadIdx.x;
    if (idx >= total) return;
    int d4 = idx & 31;
    size_t p = idx >> 5;
    int x = (int)(p % Wo); p /= Wo;
    int y = (int)(p % Ho); int t = (int)(p / Ho);
    const unsigned short* b0 = ini + (size_t)t * FRi + ((size_t)(2 * y) * PWi + 2 * x) * D_ + d4 * 4;
    const unsigned short* b1r = b0 + (size_t)PWi * D_;
    float acc[4] = {0.f, 0.f, 0.f, 0.f};
#pragma unroll
    for (int j = 0; j < 2; ++j) {
        const unsigned short* bb = j ? b1r : b0;
#pragma unroll
        for (int i = 0; i < 2; ++i) {
            const unsigned short* q = bb + i * D_;
#pragma unroll
            for (int c = 0; c < 4; ++c) acc[c] += bf2f(q[c]);
        }
    }
    unsigned short* o = outi + (size_t)t * FRo + ((size_t)y * PWo + x) * D_ + d4 * 4;
#pragma unroll
    for (int c = 0; c < 4; ++c) o[c] = f2bf(acc[c] * 0.25f);
}

// ---------------- bilinear sampler on padded map (no clamps needed) ----------
__device__ inline float2 bilin2p(const unsigned short* __restrict__ fb, int PW,
                                 float px, float py, int lane) {
    float x0f = floorf(px), y0f = floorf(py);
    float tx = px - x0f, ty = py - y0f;
    int x0 = (int)x0f, y0 = (int)y0f;
    float acc0 = 0.f, acc1 = 0.f;
#pragma unroll
    for (int dy = 0; dy < 2; ++dy) {
#pragma unroll
        for (int dx = 0; dx < 2; ++dx) {
            long xi = x0 + dx, yi = y0 + dy;
            float w = (dx ? tx : 1.f - tx) * (dy ? ty : 1.f - ty);
            unsigned int pk = *(const unsigned int*)(fb + (yi * PW + xi) * D_ + lane * 2);
            acc0 += w * bf2f((unsigned short)(pk & 0xffffu));
            acc1 += w * bf2f((unsigned short)(pk >> 16));
        }
    }
    return {acc0, acc1};
}

// ---------------- track-support features, all levels: (4,N,64,128) bf16 ------
__global__ __launch_bounds__(256) void k_tf(const unsigned short* __restrict__ f0,
                                            const unsigned short* __restrict__ f1,
                                            const unsigned short* __restrict__ f2,
                                            const unsigned short* __restrict__ f3,
                                            const float* __restrict__ qcoords,
                                            const int* __restrict__ qframes,
                                            unsigned short* __restrict__ tfg) {
    int n = blockIdx.x, lvl = blockIdx.y;
    const unsigned short* fmi = lvl == 0 ? f0 : lvl == 1 ? f1 : lvl == 2 ? f2 : f3;
    int Hs = H_ >> lvl, Ws = W_ >> lvl;
    int PW = Ws + 2 * PAD;
    size_t FR = (size_t)(Hs + 2 * PAD) * PW * D_;
    float inv = 1.0f / (float)(1 << lvl);
    int wid = threadIdx.x >> 6, lane = threadIdx.x & 63;
    int fidx = qframes[n];
    float qx = qcoords[n * 2 + 0] * inv, qy = qcoords[n * 2 + 1] * inv;
    const unsigned short* fb = fmi + (size_t)fidx * FR;
    unsigned short* orow = tfg + ((size_t)lvl * N_ + n) * (64 * D_);
    for (int k = wid; k < 64; k += 4) {
        float2 v = {0.f, 0.f};
        if (k < KP) {
            float px = qx + (float)(k / 7 - 3);
            float py = qy + (float)(k % 7 - 3);
            v = bilin2p(fb, PW, px, py, lane);
        }
        unsigned int pk = (unsigned int)f2bf(v.x) | ((unsigned int)f2bf(v.y) << 16);
        *(unsigned int*)(orow + k * D_ + lane * 2) = pk;
    }
}

// ---------------- cf + 49x49 correlation, pipelined over t ------------------
// One block per (n,lvl), 8 waves. tf staged once, B-fragments register-resident.
// P patches double-buffered via global_load_lds with counted vmcnt (never 0 in
// loop). 2 raw s_barriers per t. Padded fm => no OOB predication anywhere.
__global__ __launch_bounds__(512) void k_cfvol(const unsigned short* __restrict__ f0,
                                               const unsigned short* __restrict__ f1,
                                               const unsigned short* __restrict__ f2,
                                               const unsigned short* __restrict__ f3,
                                               const float* __restrict__ coords,
                                               const unsigned short* __restrict__ tfg,
                                               unsigned short* __restrict__ vol) {
    __shared__ unsigned char tfs[16384];
    __shared__ unsigned char Ps[2][16384];
    __shared__ float Gs[64 * 66];
    __shared__ float cS[2 * T_];
    int n = blockIdx.x, lvl = blockIdx.y;
    const unsigned short* fmi = lvl == 0 ? f0 : lvl == 1 ? f1 : lvl == 2 ? f2 : f3;
    int Hs = H_ >> lvl, Ws = W_ >> lvl;
    int PW = Ws + 2 * PAD;
    size_t FR = (size_t)(Hs + 2 * PAD) * PW * D_;
    float inv = 1.0f / (float)(1 << lvl);
    int tid = threadIdx.x, wid = tid >> 6, lane = tid & 63;
    int l15 = lane & 15, hi = lane >> 4;
    int seg = wid & 3, ch = wid >> 2;      // wave tile: G rows seg*16.., cols ch*32..

    // prologue: coords -> LDS; stage tf; stage P0
    if (tid < 2 * T_)
        cS[tid] = coords[((size_t)(tid >> 1) * N_ + n) * 2 + (tid & 1)] * inv;
    const unsigned short* tfn = tfg + ((size_t)lvl * N_ + n) * (64 * D_);
#pragma unroll
    for (int i = 0; i < 2; ++i) {
        int rr = wid * 8 + i * 4 + hi;
        int u = l15 ^ (rr & 7);
        GLOAD16(tfn + rr * 128 + u * 8, tfs + (wid * 2 + i) * 1024);
    }
    auto stageP = [&](int t, unsigned char* dst, float cx, float cy) {
        long bx = (long)(int)floorf(cx) - 3, by = (long)(int)floorf(cy) - 3;
        const unsigned short* fb = fmi + (size_t)t * FR;
#pragma unroll
        for (int i = 0; i < 2; ++i) {
            int rr = wid * 8 + i * 4 + hi;
            int u = l15 ^ (rr & 7);
            GLOAD16(fb + ((by + (rr & 7)) * (long)PW + (bx + (rr >> 3))) * D_ + u * 8,
                    dst + (wid * 2 + i) * 1024);
        }
    };
    {
        float cx = coords[(size_t)n * 2 + 0] * inv;
        float cy = coords[(size_t)n * 2 + 1] * inv;
        stageP(0, Ps[0], cx, cy);
    }
    asm volatile("s_waitcnt vmcnt(2) lgkmcnt(0)" ::: "memory");
    __builtin_amdgcn_s_barrier();
    // register-resident B fragments from tf
    bf16x8 bfr[2][4];
#pragma unroll
    for (int ln = 0; ln < 2; ++ln)
#pragma unroll
        for (int ks = 0; ks < 4; ++ks) {
            int brow = ch * 32 + ln * 16 + l15;
            int colb = ks * 64 + hi * 16;
            bfr[ln][ks] = *(const bf16x8*)(tfs + brow * 256 + (colb ^ ((brow & 7) << 4)));
        }
    auto mfmaPhase = [&](const unsigned char* PB) {
        f32x4 acc[2] = {f32x4{0, 0, 0, 0}, f32x4{0, 0, 0, 0}};
#pragma unroll
        for (int ks = 0; ks < 4; ++ks) {
            int arow = seg * 16 + l15;
            int colb = ks * 64 + hi * 16;
            bf16x8 a = *(const bf16x8*)(PB + arow * 256 + (colb ^ ((arow & 7) << 4)));
#pragma unroll
            for (int ln = 0; ln < 2; ++ln)
                acc[ln] = __builtin_amdgcn_mfma_f32_16x16x32_bf16(a, bfr[ln][ks], acc[ln], 0, 0, 0);
        }
#pragma unroll
        for (int ln = 0; ln < 2; ++ln)
#pragma unroll
            for (int r = 0; r < 4; ++r)
                Gs[(seg * 16 + hi * 4 + r) * 66 + ch * 32 + ln * 16 + l15] = acc[ln][r];
    };
    auto combine = [&](int t) {
        float cx = cS[t * 2], cy = cS[t * 2 + 1];
        float tx = cx - floorf(cx), ty = cy - floorf(cy);
        float w00 = (1.f - tx) * (1.f - ty), w01 = (1.f - tx) * ty;
        float w10 = tx * (1.f - ty), w11 = tx * ty;
        unsigned int* vrow = (unsigned int*)(vol + (((size_t)lvl * T_ + t) * N_ + n) * K2);
        int lh = lane >> 5, ll = lane & 31;
#pragma unroll
        for (int it = 0; it < 4; ++it) {
            int k = it * 16 + wid * 2 + lh;
            if (k > 48) k = 48;   // duplicate write of identical bytes (uniform store count)
            int a0 = k / 7, b0 = k - a0 * 7;
            int g = a0 * 8 + b0;
            const float* gp = &Gs[g * 66 + ll * 2];
            float2 v00 = *(const float2*)gp;
            float2 v01 = *(const float2*)(gp + 66);
            float2 v10 = *(const float2*)(gp + 8 * 66);
            float2 v11 = *(const float2*)(gp + 9 * 66);
            float r0 = w00 * v00.x + w01 * v01.x + w10 * v10.x + w11 * v11.x;
            float r1 = w00 * v00.y + w01 * v01.y + w10 * v10.y + w11 * v11.y;
            vrow[k * 32 + ll] = (unsigned int)f2bf(r0) | ((unsigned int)f2bf(r1) << 16);
        }
    };
    // t = 0 (peeled: no stores outstanding yet)
    stageP(1, Ps[1], cS[2], cS[3]);
    asm volatile("s_waitcnt vmcnt(2)" ::: "memory");
    __builtin_amdgcn_s_barrier();
    mfmaPhase(Ps[0]);
    asm volatile("s_waitcnt lgkmcnt(0)" ::: "memory");
    __builtin_amdgcn_s_barrier();
    combine(0);
    // steady state: outstanding after wait = stores(t-1) x4 + loads(t+1) x2 = 6
    for (int t = 1; t < T_ - 1; ++t) {
        stageP(t + 1, Ps[(t + 1) & 1], cS[(t + 1) * 2], cS[(t + 1) * 2 + 1]);
        asm volatile("s_waitcnt vmcnt(6)" ::: "memory");
        __builtin_amdgcn_s_barrier();
        mfmaPhase(Ps[t & 1]);
        asm volatile("s_waitcnt lgkmcnt(0)" ::: "memory");
        __builtin_amdgcn_s_barrier();
        combine(t);
    }
    // t = 23
    asm volatile("s_waitcnt vmcnt(4)" ::: "memory");
    __builtin_amdgcn_s_barrier();
    mfmaPhase(Ps[1]);
    asm volatile("s_waitcnt lgkmcnt(0)" ::: "memory");
    __builtin_amdgcn_s_barrier();
    combine(T_ - 1);
}

// ---------------- GEMM1: (24576 x K2) @ w1t^T (384 x K2), BM=128 BN=64 -------
__global__ __launch_bounds__(256) void k_gemm1(const unsigned short* __restrict__ A,
                                               const unsigned short* __restrict__ Bt,
                                               const float* __restrict__ b1,
                                               unsigned short* __restrict__ Hout) {
    __shared__ unsigned char As[16384];   // 128 rows x 128B, swizzled content
    __shared__ unsigned char Bs[8192];    // 64 rows x 128B
    int bm = blockIdx.x / 6, bn = blockIdx.x % 6;   // A-panel-major for L3 reuse
    int tid = threadIdx.x, lane = tid & 63;
    int wid = tid >> 6, wm = wid & 1, wn = wid >> 1;
    int l15 = lane & 15, hi = lane >> 4;
    f32x4 acc[4][2] = {};
    const unsigned short* Abase = A + (size_t)(bm * 128) * K2;
    const unsigned short* Bbase = Bt + (size_t)(bn * 64) * K2;
    for (int kt = 0; kt < K2 / 64; ++kt) {
#pragma unroll
        for (int q = 0; q < 4; ++q) {
            int e = (wid * 4 + q) * 64 + lane;
            int row = e >> 3, su = (e & 7) ^ (row & 7);
            GLOAD16(Abase + (size_t)row * K2 + kt * 64 + su * 8, As + (wid * 4 + q) * 1024);
        }
#pragma unroll
        for (int q = 0; q < 2; ++q) {
            int e = (wid * 2 + q) * 64 + lane;
            int row = e >> 3, su = (e & 7) ^ (row & 7);
            GLOAD16(Bbase + (size_t)row * K2 + kt * 64 + su * 8, Bs + (wid * 2 + q) * 1024);
        }
        __syncthreads();
#pragma unroll
        for (int ks = 0; ks < 2; ++ks) {
            int colb = ks * 64 + hi * 16;
            bf16x8 a[4], b[2];
#pragma unroll
            for (int km = 0; km < 4; ++km) {
                int arow = wm * 64 + km * 16 + l15;
                a[km] = *(const bf16x8*)(As + arow * 128 + (colb ^ ((arow & 7) << 4)));
            }
#pragma unroll
            for (int ln = 0; ln < 2; ++ln) {
                int brow = wn * 32 + ln * 16 + l15;
                b[ln] = *(const bf16x8*)(Bs + brow * 128 + (colb ^ ((brow & 7) << 4)));
            }
#pragma unroll
            for (int km = 0; km < 4; ++km)
#pragma unroll
                for (int ln = 0; ln < 2; ++ln)
                    acc[km][ln] = __builtin_amdgcn_mfma_f32_16x16x32_bf16(a[km], b[ln], acc[km][ln], 0, 0, 0);
        }
        __syncthreads();
    }
#pragma unroll
    for (int km = 0; km < 4; ++km)
#pragma unroll
        for (int ln = 0; ln < 2; ++ln)
#pragma unroll
            for (int r = 0; r < 4; ++r) {
                int row = bm * 128 + wm * 64 + km * 16 + hi * 4 + r;
                int col = bn * 64 + wn * 32 + ln * 16 + l15;
                float x = acc[km][ln][r] + b1[col];
                float g = 0.5f * x * (1.f + erff(x * 0.70710678118654752f));
                Hout[(size_t)row * H1 + col] = f2bf(g);
            }
}

// ---------------- GEMM2 (batched): (24576 x 384) @ w2t^T (256 x 384) ---------
__global__ __launch_bounds__(256) void k_gemm2(const unsigned short* __restrict__ A,
                                               const unsigned short* __restrict__ Bt,
                                               const float* __restrict__ b2,
                                               float* __restrict__ outp) {
    __shared__ unsigned char As[16384];   // 128 x 128B
    __shared__ unsigned char Bs[8192];    // 64 x 128B
    int bm = blockIdx.x >> 2, bn = blockIdx.x & 3;  // A-panel-major
    int tid = threadIdx.x, lane = tid & 63;
    int wid = tid >> 6, wm = wid & 1, wn = wid >> 1;
    int l15 = lane & 15, hi = lane >> 4;
    f32x4 acc[4][2] = {};
    const unsigned short* Abase = A + (size_t)(bm * 128) * H1;
    const unsigned short* Bbase = Bt + (size_t)(bn * 64) * H1;
    for (int kt = 0; kt < H1 / 64; ++kt) {
#pragma unroll
        for (int q = 0; q < 4; ++q) {
            int e = (wid * 4 + q) * 64 + lane;
            int row = e >> 3, su = (e & 7) ^ (row & 7);
            GLOAD16(Abase + (size_t)row * H1 + kt * 64 + su * 8, As + (wid * 4 + q) * 1024);
        }
#pragma unroll
        for (int q = 0; q < 2; ++q) {
            int e = (wid * 2 + q) * 64 + lane;
            int row = e >> 3, su = (e & 7) ^ (row & 7);
            GLOAD16(Bbase + (size_t)row * H1 + kt * 64 + su * 8, Bs + (wid * 2 + q) * 1024);
        }
        __syncthreads();
#pragma unroll
        for (int ks = 0; ks < 2; ++ks) {
            int colb = ks * 64 + hi * 16;
            bf16x8 a[4], b[2];
#pragma unroll
            for (int km = 0; km < 4; ++km) {
                int arow = wm * 64 + km * 16 + l15;
                a[km] = *(const bf16x8*)(As + arow * 128 + (colb ^ ((arow & 7) << 4)));
            }
#pragma unroll
            for (int ln = 0; ln < 2; ++ln) {
                int brow = wn * 32 + ln * 16 + l15;
                b[ln] = *(const bf16x8*)(Bs + brow * 128 + (colb ^ ((brow & 7) << 4)));
            }
#pragma unroll
            for (int km = 0; km < 4; ++km)
#pragma unroll
                for (int ln = 0; ln < 2; ++ln)
                    acc[km][ln] = __builtin_amdgcn_mfma_f32_16x16x32_bf16(a[km], b[ln], acc[km][ln], 0, 0, 0);
        }
        __syncthreads();
    }
#pragma unroll
    for (int km = 0; km < 4; ++km)
#pragma unroll
        for (int ln = 0; ln < 2; ++ln)
#pragma unroll
            for (int r = 0; r < 4; ++r) {
                int row = bm * 128 + wm * 64 + km * 16 + hi * 4 + r;
                int col = bn * 64 + wn * 32 + ln * 16 + l15;
                int lvl = row / (T_ * N_);
                int r2 = row - lvl * (T_ * N_);
                outp[(size_t)r2 * (4 * OUTC) + lvl * OUTC + col] = acc[km][ln][r] + b2[col];
            }
}

extern "C" void kernel_launch(void* const* d_in, const int* in_sizes, int n_in,
                              void* d_out, int out_size, void* d_ws, size_t ws_size,
                              hipStream_t stream) {
    const float* fmaps   = (const float*)d_in[0];
    const float* coords  = (const float*)d_in[1];
    const float* qcoords = (const float*)d_in[2];
    const int*   qframes = (const int*)d_in[3];
    const float* w1      = (const float*)d_in[4];
    const float* b1      = (const float*)d_in[5];
    const float* w2      = (const float*)d_in[6];
    const float* b2      = (const float*)d_in[7];
    float* outp = (float*)d_out;

    unsigned char* ws = (unsigned char*)d_ws;
    size_t off = 0;
    auto take = [&](size_t bytes) {
        unsigned char* p = ws + off;
        off += (bytes + 255) & ~(size_t)255;
        return p;
    };
    // padded pyramid buffers
    const int Hs[4] = {96, 48, 24, 12}, Wss[4] = {128, 64, 32, 16};
    unsigned short* fmraw[4];
    unsigned short* fmint[4];
    for (int l = 0; l < 4; ++l) {
        int PH = Hs[l] + 2 * PAD, PW = Wss[l] + 2 * PAD;
        fmraw[l] = (unsigned short*)take((size_t)T_ * PH * PW * D_ * 2);
        fmint[l] = fmraw[l] + ((size_t)PAD * PW + PAD) * D_;
    }
    unsigned short* tfg  = (unsigned short*)take((size_t)4 * N_ * 64 * D_ * 2);
    unsigned short* vol  = (unsigned short*)take((size_t)MTOT * K2 * 2);
    unsigned short* hbuf = (unsigned short*)take((size_t)MTOT * H1 * 2);
    unsigned short* w1t  = (unsigned short*)take((size_t)H1 * K2 * 2);
    unsigned short* w2t  = (unsigned short*)take((size_t)OUTC * H1 * 2);

    for (int l = 0; l < 4; ++l)
        hipLaunchKernelGGL(k_padzero, dim3(4096), dim3(256), 0, stream,
                           (uint4*)fmraw[l], Hs[l], Wss[l]);
    hipLaunchKernelGGL(k_w1t, dim3((H1 * K2 + 255) / 256), dim3(256), 0, stream, w1, w1t);
    hipLaunchKernelGGL(k_w2t, dim3((OUTC * H1 + 255) / 256), dim3(256), 0, stream, w2, w2t);
    hipLaunchKernelGGL(k_normalize, dim3(T_ * H_), dim3(256), 0, stream, fmaps, fmint[0]);
    hipLaunchKernelGGL(k_pool, dim3((T_ * 48 * 64 * 32 + 255) / 256), dim3(256), 0, stream,
                       fmint[0], fmint[1], 96, 128);
    hipLaunchKernelGGL(k_pool, dim3((T_ * 24 * 32 * 32 + 255) / 256), dim3(256), 0, stream,
                       fmint[1], fmint[2], 48, 64);
    hipLaunchKernelGGL(k_pool, dim3((T_ * 12 * 16 * 32 + 255) / 256), dim3(256), 0, stream,
                       fmint[2], fmint[3], 24, 32);

    hipLaunchKernelGGL(k_tf, dim3(N_, 4), dim3(256), 0, stream,
                       fmint[0], fmint[1], fmint[2], fmint[3], qcoords, qframes, tfg);
    hipLaunchKernelGGL(k_cfvol, dim3(N_, 4), dim3(512), 0, stream,
                       fmint[0], fmint[1], fmint[2], fmint[3], coords, tfg, vol);
    hipLaunchKernelGGL(k_gemm1, dim3((MTOT / 128) * 6), dim3(256), 0, stream, vol, w1t, b1, hbuf);
    hipLaunchKernelGGL(k_gemm2, dim3((MTOT / 128) * 4), dim3(256), 0, stream, hbuf, w2t, b2, outp);
}

// Round 5
// 328.202 us; speedup vs baseline: 1.1624x; 1.1624x over previous
//
#include <hip/hip_runtime.h>
#include <hip/hip_bf16.h>
#include <stdint.h>

// Problem constants (fixed by setup_inputs)
#define T_   24
#define D_   128
#define H_   96
#define W_   128
#define N_   256
#define KP   49      // 7x7 support points
#define K2   3136    // vol K-dim: 49 k-rows x 64 l-slots (l>=49 zero-padded)
#define H1   384     // MLP hidden
#define OUTC 256     // MLP out
#define MTOT (4 * T_ * N_)   // 24576 rows batched over levels

// padded pyramid geometry (8-px zero border on all sides)
#define PAD  8

typedef __attribute__((ext_vector_type(8))) __bf16 bf16x8;
typedef __attribute__((ext_vector_type(4))) float f32x4;

typedef __attribute__((address_space(3))) unsigned int lds_u32;
typedef const __attribute__((address_space(1))) unsigned int g_u32;
#define GLOAD16(g, l) __builtin_amdgcn_global_load_lds((g_u32*)(g), (lds_u32*)(l), 16, 0, 0)

__device__ inline float bf2f(unsigned short u) {
    union { unsigned int i; float f; } v; v.i = ((unsigned int)u) << 16; return v.f;
}
__device__ inline unsigned short f2bf(float f) {
    union { float f; unsigned int i; } v; v.f = f;
    unsigned int i = v.i;
    return (unsigned short)((i + 0x7FFFu + ((i >> 16) & 1u)) >> 16);  // RNE
}

// ---------------- pad zero: border of each padded level buffer ---------------
__global__ __launch_bounds__(256) void k_padzero(uint4* __restrict__ fm,
                                                 int Hs, int Ws) {
    int PW = Ws + 2 * PAD, PH = Hs + 2 * PAD;
    size_t upf = (size_t)PH * PW * 16;   // uint4 units per frame (128 shorts/px)
    size_t total = upf * T_;
    for (size_t idx = (size_t)blockIdx.x * 256 + threadIdx.x; idx < total;
         idx += (size_t)gridDim.x * 256) {
        size_t p = idx >> 4;
        size_t pf = p % ((size_t)PH * PW);
        int y = (int)(pf / PW), x = (int)(pf % PW);
        if (y < PAD || y >= Hs + PAD || x < PAD || x >= Ws + PAD) {
            uint4 z = {0u, 0u, 0u, 0u};
            fm[idx] = z;
        }
    }
}

// ---------------- weight transpose/convert (one-time per call) ----------------
// w1t layout: [n][k*64 + l], l>=49 zero (matches vol layout)
__global__ __launch_bounds__(256) void k_w1t(const float* __restrict__ w1,
                                             unsigned short* __restrict__ w1t) {
    int idx = blockIdx.x * 256 + threadIdx.x;           // H1*K2
    if (idx >= H1 * K2) return;
    int nn = idx / K2, kk = idx % K2;
    int k = kk >> 6, l = kk & 63;
    float v = (l < KP) ? w1[((size_t)k * KP + l) * H1 + nn] : 0.f;
    w1t[idx] = f2bf(v);
}
__global__ __launch_bounds__(256) void k_w2t(const float* __restrict__ w2,
                                             unsigned short* __restrict__ w2t) {
    int idx = blockIdx.x * 256 + threadIdx.x;           // OUTC*H1
    if (idx >= OUTC * H1) return;
    int j = idx / H1, k = idx % H1;
    w2t[idx] = f2bf(w2[(size_t)k * OUTC + j]);
}

// ---------------- L2 normalize + transpose -> padded (T,H,W,D) bf16 ----------
// Single read of fmaps: stage f32 tile in LDS during ssq pass, scale at write.
#define PW0 (W_ + 2 * PAD)
#define FR0 ((size_t)(H_ + 2 * PAD) * PW0 * D_)
__global__ __launch_bounds__(256) void k_normalize(const float* __restrict__ fmaps,
                                                   unsigned short* __restrict__ fm0i) {
    int bid = blockIdx.x;                 // t*H_ + h
    int t = bid / H_, h = bid % H_;
    int tid = threadIdx.x;
    __shared__ float tile[64 * 129];
    __shared__ float ssumP[64][4];
    __shared__ float rs[64];
    const float* base = fmaps + (size_t)t * D_ * H_ * W_ + (size_t)h * W_;
    unsigned short* orow = fm0i + (size_t)t * FR0 + (size_t)h * (PW0 * D_);
    for (int wt = 0; wt < 2; ++wt) {
        int wl = tid & 63, dg = tid >> 6;
        float ss = 0.f;
        for (int i = 0; i < 32; ++i) {
            int d = dg * 32 + i;
            float v = base[(size_t)d * (H_ * W_) + wt * 64 + wl];
            tile[wl * 129 + d] = v;
            ss += v * v;
        }
        ssumP[wl][dg] = ss;
        __syncthreads();
        if (tid < 64)
            rs[tid] = rsqrtf(fmaxf(ssumP[tid][0] + ssumP[tid][1] + ssumP[tid][2] + ssumP[tid][3], 1e-12f));
        __syncthreads();
        int c = tid & 63, rg = tid >> 6;      // u32 col (2 d's), row group
        for (int i = 0; i < 16; ++i) {
            int wll = rg * 16 + i;
            float r = rs[wll];
            float v0 = tile[wll * 129 + c * 2] * r;
            float v1 = tile[wll * 129 + c * 2 + 1] * r;
            *(unsigned int*)(orow + (size_t)(wt * 64 + wll) * D_ + c * 2) =
                (unsigned int)f2bf(v0) | ((unsigned int)f2bf(v1) << 16);
        }
        __syncthreads();
    }
}

// ---------------- 2x2 avg pool on padded buffers -----------------------------
__global__ __launch_bounds__(256) void k_pool(const unsigned short* __restrict__ ini,
                                              unsigned short* __restrict__ outi,
                                              int Hs, int Ws) {
    int Ho = Hs >> 1, Wo = Ws >> 1;
    int PWi = Ws + 2 * PAD, PWo = Wo + 2 * PAD;
    size_t FRi = (size_t)(Hs + 2 * PAD) * PWi * D_;
    size_t FRo = (size_t)(Ho + 2 * PAD) * PWo * D_;
    size_t total = (size_t)T_ * Ho * Wo * (D_ / 4);
    size_t idx = (size_t)blockIdx.x * 256 + threadIdx.x;
    if (idx >= total) return;
    int d4 = idx & 31;
    size_t p = idx >> 5;
    int x = (int)(p % Wo); p /= Wo;
    int y = (int)(p % Ho); int t = (int)(p / Ho);
    const unsigned short* b0 = ini + (size_t)t * FRi + ((size_t)(2 * y) * PWi + 2 * x) * D_ + d4 * 4;
    const unsigned short* b1r = b0 + (size_t)PWi * D_;
    float acc[4] = {0.f, 0.f, 0.f, 0.f};
#pragma unroll
    for (int j = 0; j < 2; ++j) {
        const unsigned short* bb = j ? b1r : b0;
#pragma unroll
        for (int i = 0; i < 2; ++i) {
            const unsigned short* q = bb + i * D_;
#pragma unroll
            for (int c = 0; c < 4; ++c) acc[c] += bf2f(q[c]);
        }
    }
    unsigned short* o = outi + (size_t)t * FRo + ((size_t)y * PWo + x) * D_ + d4 * 4;
#pragma unroll
    for (int c = 0; c < 4; ++c) o[c] = f2bf(acc[c] * 0.25f);
}

// ---------------- bilinear sampler on padded map (no clamps needed) ----------
__device__ inline float2 bilin2p(const unsigned short* __restrict__ fb, int PW,
                                 float px, float py, int lane) {
    float x0f = floorf(px), y0f = floorf(py);
    float tx = px - x0f, ty = py - y0f;
    int x0 = (int)x0f, y0 = (int)y0f;
    float acc0 = 0.f, acc1 = 0.f;
#pragma unroll
    for (int dy = 0; dy < 2; ++dy) {
#pragma unroll
        for (int dx = 0; dx < 2; ++dx) {
            long xi = x0 + dx, yi = y0 + dy;
            float w = (dx ? tx : 1.f - tx) * (dy ? ty : 1.f - ty);
            unsigned int pk = *(const unsigned int*)(fb + (yi * PW + xi) * D_ + lane * 2);
            acc0 += w * bf2f((unsigned short)(pk & 0xffffu));
            acc1 += w * bf2f((unsigned short)(pk >> 16));
        }
    }
    return {acc0, acc1};
}

// ---------------- track-support features, all levels: (4,N,64,128) bf16 ------
__global__ __launch_bounds__(256) void k_tf(const unsigned short* __restrict__ f0,
                                            const unsigned short* __restrict__ f1,
                                            const unsigned short* __restrict__ f2,
                                            const unsigned short* __restrict__ f3,
                                            const float* __restrict__ qcoords,
                                            const int* __restrict__ qframes,
                                            unsigned short* __restrict__ tfg) {
    int n = blockIdx.x, lvl = blockIdx.y;
    const unsigned short* fmi = lvl == 0 ? f0 : lvl == 1 ? f1 : lvl == 2 ? f2 : f3;
    int Hs = H_ >> lvl, Ws = W_ >> lvl;
    int PW = Ws + 2 * PAD;
    size_t FR = (size_t)(Hs + 2 * PAD) * PW * D_;
    float inv = 1.0f / (float)(1 << lvl);
    int wid = threadIdx.x >> 6, lane = threadIdx.x & 63;
    int fidx = qframes[n];
    float qx = qcoords[n * 2 + 0] * inv, qy = qcoords[n * 2 + 1] * inv;
    const unsigned short* fb = fmi + (size_t)fidx * FR;
    unsigned short* orow = tfg + ((size_t)lvl * N_ + n) * (64 * D_);
    for (int k = wid; k < 64; k += 4) {
        float2 v = {0.f, 0.f};
        if (k < KP) {
            float px = qx + (float)(k / 7 - 3);
            float py = qy + (float)(k % 7 - 3);
            v = bilin2p(fb, PW, px, py, lane);
        }
        unsigned int pk = (unsigned int)f2bf(v.x) | ((unsigned int)f2bf(v.y) << 16);
        *(unsigned int*)(orow + k * D_ + lane * 2) = pk;
    }
}

// ---------------- cf + 49x49 correlation via shared 8x8 patch ---------------
// One block per (n,t,lvl). All staging pure global_load_lds with pre-swizzled
// sources (padded fm => no predication). G = P . tf^T via 64 MFMAs, then
// 4-tap combine -> coalesced packed stores. 2 barriers per block.
__global__ __launch_bounds__(256) void k_cfvol(const unsigned short* __restrict__ f0,
                                               const unsigned short* __restrict__ f1,
                                               const unsigned short* __restrict__ f2,
                                               const unsigned short* __restrict__ f3,
                                               const float* __restrict__ coords,
                                               const unsigned short* __restrict__ tfg,
                                               unsigned short* __restrict__ vol) {
    __shared__ unsigned char tfs[16384];
    __shared__ unsigned char Ps[16384];
    __shared__ float Gs[64 * 66];
    int n = blockIdx.x, t = blockIdx.y, lvl = blockIdx.z;
    const unsigned short* fmi = lvl == 0 ? f0 : lvl == 1 ? f1 : lvl == 2 ? f2 : f3;
    int Hs = H_ >> lvl, Ws = W_ >> lvl;
    int PW = Ws + 2 * PAD;
    size_t FR = (size_t)(Hs + 2 * PAD) * PW * D_;
    float inv = 1.0f / (float)(1 << lvl);
    int tid = threadIdx.x, wid = tid >> 6, lane = tid & 63;
    int l15 = lane & 15, hi = lane >> 4;

    float cx = coords[((size_t)t * N_ + n) * 2 + 0] * inv;
    float cy = coords[((size_t)t * N_ + n) * 2 + 1] * inv;
    float fx = floorf(cx), fy = floorf(cy);
    float tx = cx - fx, ty = cy - fy;
    long bx = (long)(int)fx - 3, by = (long)(int)fy - 3;
    const unsigned short* fb = fmi + (size_t)t * FR;
    const unsigned short* tfn = tfg + ((size_t)lvl * N_ + n) * (64 * D_);
    // stage tf (16 gload16, 4/wave); LDS linear, source pre-swizzled
#pragma unroll
    for (int i = 0; i < 4; ++i) {
        int rr = wid * 16 + i * 4 + hi;
        int u = l15 ^ (rr & 7);
        GLOAD16(tfn + rr * 128 + u * 8, tfs + (wid * 4 + i) * 1024);
    }
    // stage P: row rr -> pixel (a = rr>>3, b = rr&7)
#pragma unroll
    for (int i = 0; i < 4; ++i) {
        int rr = wid * 16 + i * 4 + hi;
        int u = l15 ^ (rr & 7);
        GLOAD16(fb + ((by + (rr & 7)) * (long)PW + (bx + (rr >> 3))) * D_ + u * 8,
                Ps + (wid * 4 + i) * 1024);
    }
    asm volatile("s_waitcnt vmcnt(0)" ::: "memory");
    __builtin_amdgcn_s_barrier();
    // G = P . tf^T : wave wid computes G rows [wid*16, wid*16+16)
    f32x4 acc[4] = {f32x4{0,0,0,0}, f32x4{0,0,0,0}, f32x4{0,0,0,0}, f32x4{0,0,0,0}};
#pragma unroll
    for (int ks = 0; ks < 4; ++ks) {
        int colb = ks * 64 + hi * 16;
        int arow = wid * 16 + l15;
        bf16x8 a = *(const bf16x8*)(Ps + arow * 256 + (colb ^ ((arow & 7) << 4)));
#pragma unroll
        for (int ln = 0; ln < 4; ++ln) {
            int brow = ln * 16 + l15;
            bf16x8 b = *(const bf16x8*)(tfs + brow * 256 + (colb ^ ((brow & 7) << 4)));
            acc[ln] = __builtin_amdgcn_mfma_f32_16x16x32_bf16(a, b, acc[ln], 0, 0, 0);
        }
    }
#pragma unroll
    for (int ln = 0; ln < 4; ++ln)
#pragma unroll
        for (int r = 0; r < 4; ++r)
            Gs[(wid * 16 + hi * 4 + r) * 66 + ln * 16 + l15] = acc[ln][r];
    __syncthreads();
    // combine: vol[k*64+l] = w00*G[g,l]+w01*G[g+1,l]+w10*G[g+8,l]+w11*G[g+9,l]
    unsigned int* vrow = (unsigned int*)(vol + (((size_t)lvl * T_ + t) * N_ + n) * K2);
    float w00 = (1.f - tx) * (1.f - ty), w01 = (1.f - tx) * ty;
    float w10 = tx * (1.f - ty), w11 = tx * ty;
    int lh = lane >> 5, ll = lane & 31;
#pragma unroll
    for (int it = 0; it < 7; ++it) {
        int k = it * 8 + wid * 2 + lh;
        if (k < KP) {
            int a0 = k / 7, b0 = k - a0 * 7;
            int g = a0 * 8 + b0;
            const float* gp = &Gs[g * 66 + ll * 2];
            float2 v00 = *(const float2*)gp;
            float2 v01 = *(const float2*)(gp + 66);
            float2 v10 = *(const float2*)(gp + 8 * 66);
            float2 v11 = *(const float2*)(gp + 9 * 66);
            float r0 = w00 * v00.x + w01 * v01.x + w10 * v10.x + w11 * v11.x;
            float r1 = w00 * v00.y + w01 * v01.y + w10 * v10.y + w11 * v11.y;
            vrow[k * 32 + ll] = (unsigned int)f2bf(r0) | ((unsigned int)f2bf(r1) << 16);
        }
    }
}

// ---------------- GEMM1: (24576 x K2) @ w1t^T (384 x K2), BM=64 BN=128 -------
// XCD-swizzled grid, bn-fastest within chunk: A-panel sharers co-locate on XCD.
__global__ __launch_bounds__(256) void k_gemm1(const unsigned short* __restrict__ A,
                                               const unsigned short* __restrict__ Bt,
                                               const float* __restrict__ b1,
                                               unsigned short* __restrict__ Hout) {
    __shared__ unsigned char As[8192];    // 64 rows x 128B, swizzled content
    __shared__ unsigned char Bs[16384];   // 128 rows x 128B
    int bid = blockIdx.x;                           // nwg = 1152 = 8 * 144
    int swz = (bid & 7) * 144 + (bid >> 3);
    int bm = swz / 3, bn = swz % 3;
    int tid = threadIdx.x, lane = tid & 63;
    int wid = tid >> 6, wm = wid & 1, wn = wid >> 1;
    int l15 = lane & 15, hi = lane >> 4;
    f32x4 acc[2][4] = {};
    const unsigned short* Abase = A + (size_t)(bm * 64) * K2;
    const unsigned short* Bbase = Bt + (size_t)(bn * 128) * K2;
    for (int kt = 0; kt < K2 / 64; ++kt) {
#pragma unroll
        for (int q = 0; q < 2; ++q) {
            int e = (wid * 2 + q) * 64 + lane;
            int row = e >> 3, su = (e & 7) ^ (row & 7);
            GLOAD16(Abase + (size_t)row * K2 + kt * 64 + su * 8, As + (wid * 2 + q) * 1024);
        }
#pragma unroll
        for (int q = 0; q < 4; ++q) {
            int e = (wid * 4 + q) * 64 + lane;
            int row = e >> 3, su = (e & 7) ^ (row & 7);
            GLOAD16(Bbase + (size_t)row * K2 + kt * 64 + su * 8, Bs + (wid * 4 + q) * 1024);
        }
        __syncthreads();
#pragma unroll
        for (int ks = 0; ks < 2; ++ks) {
            int colb = ks * 64 + hi * 16;
            bf16x8 a[2], b[4];
#pragma unroll
            for (int km = 0; km < 2; ++km) {
                int arow = wm * 32 + km * 16 + l15;
                a[km] = *(const bf16x8*)(As + arow * 128 + (colb ^ ((arow & 7) << 4)));
            }
#pragma unroll
            for (int ln = 0; ln < 4; ++ln) {
                int brow = wn * 64 + ln * 16 + l15;
                b[ln] = *(const bf16x8*)(Bs + brow * 128 + (colb ^ ((brow & 7) << 4)));
            }
#pragma unroll
            for (int km = 0; km < 2; ++km)
#pragma unroll
                for (int ln = 0; ln < 4; ++ln)
                    acc[km][ln] = __builtin_amdgcn_mfma_f32_16x16x32_bf16(a[km], b[ln], acc[km][ln], 0, 0, 0);
        }
        __syncthreads();
    }
#pragma unroll
    for (int km = 0; km < 2; ++km)
#pragma unroll
        for (int ln = 0; ln < 4; ++ln)
#pragma unroll
            for (int r = 0; r < 4; ++r) {
                int row = bm * 64 + wm * 32 + km * 16 + hi * 4 + r;
                int col = bn * 128 + wn * 64 + ln * 16 + l15;
                float x = acc[km][ln][r] + b1[col];
                float g = 0.5f * x * (1.f + erff(x * 0.70710678118654752f));
                Hout[(size_t)row * H1 + col] = f2bf(g);
            }
}

// ---------------- GEMM2: (24576 x 384) @ w2t^T (256 x 384), BM=64 BN=128 -----
__global__ __launch_bounds__(256) void k_gemm2(const unsigned short* __restrict__ A,
                                               const unsigned short* __restrict__ Bt,
                                               const float* __restrict__ b2,
                                               float* __restrict__ outp) {
    __shared__ unsigned char As[8192];    // 64 x 128B
    __shared__ unsigned char Bs[16384];   // 128 x 128B
    int bid = blockIdx.x;                           // nwg = 768 = 8 * 96
    int swz = (bid & 7) * 96 + (bid >> 3);
    int bm = swz >> 1, bn = swz & 1;
    int tid = threadIdx.x, lane = tid & 63;
    int wid = tid >> 6, wm = wid & 1, wn = wid >> 1;
    int l15 = lane & 15, hi = lane >> 4;
    f32x4 acc[2][4] = {};
    const unsigned short* Abase = A + (size_t)(bm * 64) * H1;
    const unsigned short* Bbase = Bt + (size_t)(bn * 128) * H1;
    for (int kt = 0; kt < H1 / 64; ++kt) {
#pragma unroll
        for (int q = 0; q < 2; ++q) {
            int e = (wid * 2 + q) * 64 + lane;
            int row = e >> 3, su = (e & 7) ^ (row & 7);
            GLOAD16(Abase + (size_t)row * H1 + kt * 64 + su * 8, As + (wid * 2 + q) * 1024);
        }
#pragma unroll
        for (int q = 0; q < 4; ++q) {
            int e = (wid * 4 + q) * 64 + lane;
            int row = e >> 3, su = (e & 7) ^ (row & 7);
            GLOAD16(Bbase + (size_t)row * H1 + kt * 64 + su * 8, Bs + (wid * 4 + q) * 1024);
        }
        __syncthreads();
#pragma unroll
        for (int ks = 0; ks < 2; ++ks) {
            int colb = ks * 64 + hi * 16;
            bf16x8 a[2], b[4];
#pragma unroll
            for (int km = 0; km < 2; ++km) {
                int arow = wm * 32 + km * 16 + l15;
                a[km] = *(const bf16x8*)(As + arow * 128 + (colb ^ ((arow & 7) << 4)));
            }
#pragma unroll
            for (int ln = 0; ln < 4; ++ln) {
                int brow = wn * 64 + ln * 16 + l15;
                b[ln] = *(const bf16x8*)(Bs + brow * 128 + (colb ^ ((brow & 7) << 4)));
            }
#pragma unroll
            for (int km = 0; km < 2; ++km)
#pragma unroll
                for (int ln = 0; ln < 4; ++ln)
                    acc[km][ln] = __builtin_amdgcn_mfma_f32_16x16x32_bf16(a[km], b[ln], acc[km][ln], 0, 0, 0);
        }
        __syncthreads();
    }
#pragma unroll
    for (int km = 0; km < 2; ++km)
#pragma unroll
        for (int ln = 0; ln < 4; ++ln)
#pragma unroll
            for (int r = 0; r < 4; ++r) {
                int row = bm * 64 + wm * 32 + km * 16 + hi * 4 + r;
                int col = bn * 128 + wn * 64 + ln * 16 + l15;
                int lvl = row / (T_ * N_);
                int r2 = row - lvl * (T_ * N_);
                outp[(size_t)r2 * (4 * OUTC) + lvl * OUTC + col] = acc[km][ln][r] + b2[col];
            }
}

extern "C" void kernel_launch(void* const* d_in, const int* in_sizes, int n_in,
                              void* d_out, int out_size, void* d_ws, size_t ws_size,
                              hipStream_t stream) {
    const float* fmaps   = (const float*)d_in[0];
    const float* coords  = (const float*)d_in[1];
    const float* qcoords = (const float*)d_in[2];
    const int*   qframes = (const int*)d_in[3];
    const float* w1      = (const float*)d_in[4];
    const float* b1      = (const float*)d_in[5];
    const float* w2      = (const float*)d_in[6];
    const float* b2      = (const float*)d_in[7];
    float* outp = (float*)d_out;

    unsigned char* ws = (unsigned char*)d_ws;
    size_t off = 0;
    auto take = [&](size_t bytes) {
        unsigned char* p = ws + off;
        off += (bytes + 255) & ~(size_t)255;
        return p;
    };
    // padded pyramid buffers
    const int Hs[4] = {96, 48, 24, 12}, Wss[4] = {128, 64, 32, 16};
    unsigned short* fmraw[4];
    unsigned short* fmint[4];
    for (int l = 0; l < 4; ++l) {
        int PH = Hs[l] + 2 * PAD, PW = Wss[l] + 2 * PAD;
        fmraw[l] = (unsigned short*)take((size_t)T_ * PH * PW * D_ * 2);
        fmint[l] = fmraw[l] + ((size_t)PAD * PW + PAD) * D_;
    }
    unsigned short* tfg  = (unsigned short*)take((size_t)4 * N_ * 64 * D_ * 2);
    unsigned short* vol  = (unsigned short*)take((size_t)MTOT * K2 * 2);
    unsigned short* hbuf = (unsigned short*)take((size_t)MTOT * H1 * 2);
    unsigned short* w1t  = (unsigned short*)take((size_t)H1 * K2 * 2);
    unsigned short* w2t  = (unsigned short*)take((size_t)OUTC * H1 * 2);

    for (int l = 0; l < 4; ++l)
        hipLaunchKernelGGL(k_padzero, dim3(4096), dim3(256), 0, stream,
                           (uint4*)fmraw[l], Hs[l], Wss[l]);
    hipLaunchKernelGGL(k_w1t, dim3((H1 * K2 + 255) / 256), dim3(256), 0, stream, w1, w1t);
    hipLaunchKernelGGL(k_w2t, dim3((OUTC * H1 + 255) / 256), dim3(256), 0, stream, w2, w2t);
    hipLaunchKernelGGL(k_normalize, dim3(T_ * H_), dim3(256), 0, stream, fmaps, fmint[0]);
    hipLaunchKernelGGL(k_pool, dim3((T_ * 48 * 64 * 32 + 255) / 256), dim3(256), 0, stream,
                       fmint[0], fmint[1], 96, 128);
    hipLaunchKernelGGL(k_pool, dim3((T_ * 24 * 32 * 32 + 255) / 256), dim3(256), 0, stream,
                       fmint[1], fmint[2], 48, 64);
    hipLaunchKernelGGL(k_pool, dim3((T_ * 12 * 16 * 32 + 255) / 256), dim3(256), 0, stream,
                       fmint[2], fmint[3], 24, 32);

    hipLaunchKernelGGL(k_tf, dim3(N_, 4), dim3(256), 0, stream,
                       fmint[0], fmint[1], fmint[2], fmint[3], qcoords, qframes, tfg);
    hipLaunchKernelGGL(k_cfvol, dim3(N_, T_, 4), dim3(256), 0, stream,
                       fmint[0], fmint[1], fmint[2], fmint[3], coords, tfg, vol);
    hipLaunchKernelGGL(k_gemm1, dim3(384 * 3), dim3(256), 0, stream, vol, w1t, b1, hbuf);
    hipLaunchKernelGGL(k_gemm2, dim3(384 * 2), dim3(256), 0, stream, hbuf, w2t, b2, outp);
}

// Round 9
// 323.119 us; speedup vs baseline: 1.1807x; 1.0157x over previous
//
#include <hip/hip_runtime.h>
#include <hip/hip_bf16.h>
#include <stdint.h>

// Problem constants (fixed by setup_inputs)
#define T_   24
#define D_   128
#define H_   96
#define W_   128
#define N_   256
#define KP   49      // 7x7 support points
#define K2   3136    // vol K-dim: 49 k-rows x 64 l-slots (l>=49 zero-padded)
#define H1   384     // MLP hidden
#define OUTC 256     // MLP out
#define MTOT (4 * T_ * N_)   // 24576 rows batched over levels

// padded pyramid geometry (8-px zero border on all sides)
#define PAD  8

typedef __attribute__((ext_vector_type(8))) __bf16 bf16x8;
typedef __attribute__((ext_vector_type(4))) float f32x4;

typedef __attribute__((address_space(3))) unsigned int lds_u32;
typedef const __attribute__((address_space(1))) unsigned int g_u32;
#define GLOAD16(g, l) __builtin_amdgcn_global_load_lds((g_u32*)(g), (lds_u32*)(l), 16, 0, 0)

__device__ inline float bf2f(unsigned short u) {
    union { unsigned int i; float f; } v; v.i = ((unsigned int)u) << 16; return v.f;
}
__device__ inline unsigned short f2bf(float f) {
    union { float f; unsigned int i; } v; v.f = f;
    unsigned int i = v.i;
    return (unsigned short)((i + 0x7FFFu + ((i >> 16) & 1u)) >> 16);  // RNE
}

// ---------------- pad zero: border of each padded level buffer ---------------
__global__ __launch_bounds__(256) void k_padzero(uint4* __restrict__ fm,
                                                 int Hs, int Ws) {
    int PW = Ws + 2 * PAD, PH = Hs + 2 * PAD;
    size_t upf = (size_t)PH * PW * 16;   // uint4 units per frame (128 shorts/px)
    size_t total = upf * T_;
    for (size_t idx = (size_t)blockIdx.x * 256 + threadIdx.x; idx < total;
         idx += (size_t)gridDim.x * 256) {
        size_t p = idx >> 4;
        size_t pf = p % ((size_t)PH * PW);
        int y = (int)(pf / PW), x = (int)(pf % PW);
        if (y < PAD || y >= Hs + PAD || x < PAD || x >= Ws + PAD) {
            uint4 z = {0u, 0u, 0u, 0u};
            fm[idx] = z;
        }
    }
}

// ---------------- weight transpose/convert (one-time per call) ----------------
// w1t layout: [n][k*64 + l], l>=49 zero (matches vol layout)
__global__ __launch_bounds__(256) void k_w1t(const float* __restrict__ w1,
                                             unsigned short* __restrict__ w1t) {
    int idx = blockIdx.x * 256 + threadIdx.x;           // H1*K2
    if (idx >= H1 * K2) return;
    int nn = idx / K2, kk = idx % K2;
    int k = kk >> 6, l = kk & 63;
    float v = (l < KP) ? w1[((size_t)k * KP + l) * H1 + nn] : 0.f;
    w1t[idx] = f2bf(v);
}
__global__ __launch_bounds__(256) void k_w2t(const float* __restrict__ w2,
                                             unsigned short* __restrict__ w2t) {
    int idx = blockIdx.x * 256 + threadIdx.x;           // OUTC*H1
    if (idx >= OUTC * H1) return;
    int j = idx / H1, k = idx % H1;
    w2t[idx] = f2bf(w2[(size_t)k * OUTC + j]);
}

// ---------------- L2 normalize + transpose -> padded (T,H,W,D) bf16 ----------
// Single read of fmaps: stage f32 tile in LDS during ssq pass, scale at write.
#define PW0 (W_ + 2 * PAD)
#define FR0 ((size_t)(H_ + 2 * PAD) * PW0 * D_)
__global__ __launch_bounds__(256) void k_normalize(const float* __restrict__ fmaps,
                                                   unsigned short* __restrict__ fm0i) {
    int bid = blockIdx.x;                 // t*H_ + h
    int t = bid / H_, h = bid % H_;
    int tid = threadIdx.x;
    __shared__ float tile[64 * 129];
    __shared__ float ssumP[64][4];
    __shared__ float rs[64];
    const float* base = fmaps + (size_t)t * D_ * H_ * W_ + (size_t)h * W_;
    unsigned short* orow = fm0i + (size_t)t * FR0 + (size_t)h * (PW0 * D_);
    for (int wt = 0; wt < 2; ++wt) {
        int wl = tid & 63, dg = tid >> 6;
        float ss = 0.f;
        for (int i = 0; i < 32; ++i) {
            int d = dg * 32 + i;
            float v = base[(size_t)d * (H_ * W_) + wt * 64 + wl];
            tile[wl * 129 + d] = v;
            ss += v * v;
        }
        ssumP[wl][dg] = ss;
        __syncthreads();
        if (tid < 64)
            rs[tid] = rsqrtf(fmaxf(ssumP[tid][0] + ssumP[tid][1] + ssumP[tid][2] + ssumP[tid][3], 1e-12f));
        __syncthreads();
        int c = tid & 63, rg = tid >> 6;      // u32 col (2 d's), row group
        for (int i = 0; i < 16; ++i) {
            int wll = rg * 16 + i;
            float r = rs[wll];
            float v0 = tile[wll * 129 + c * 2] * r;
            float v1 = tile[wll * 129 + c * 2 + 1] * r;
            *(unsigned int*)(orow + (size_t)(wt * 64 + wll) * D_ + c * 2) =
                (unsigned int)f2bf(v0) | ((unsigned int)f2bf(v1) << 16);
        }
        __syncthreads();
    }
}

// ---------------- 2x2 avg pool on padded buffers -----------------------------
__global__ __launch_bounds__(256) void k_pool(const unsigned short* __restrict__ ini,
                                              unsigned short* __restrict__ outi,
                                              int Hs, int Ws) {
    int Ho = Hs >> 1, Wo = Ws >> 1;
    int PWi = Ws + 2 * PAD, PWo = Wo + 2 * PAD;
    size_t FRi = (size_t)(Hs + 2 * PAD) * PWi * D_;
    size_t FRo = (size_t)(Ho + 2 * PAD) * PWo * D_;
    size_t total = (size_t)T_ * Ho * Wo * (D_ / 4);
    size_t idx = (size_t)blockIdx.x * 256 + threadIdx.x;
    if (idx >= total) return;
    int d4 = idx & 31;
    size_t p = idx >> 5;
    int x = (int)(p % Wo); p /= Wo;
    int y = (int)(p % Ho); int t = (int)(p / Ho);
    const unsigned short* b0 = ini + (size_t)t * FRi + ((size_t)(2 * y) * PWi + 2 * x) * D_ + d4 * 4;
    const unsigned short* b1r = b0 + (size_t)PWi * D_;
    float acc[4] = {0.f, 0.f, 0.f, 0.f};
#pragma unroll
    for (int j = 0; j < 2; ++j) {
        const unsigned short* bb = j ? b1r : b0;
#pragma unroll
        for (int i = 0; i < 2; ++i) {
            const unsigned short* q = bb + i * D_;
#pragma unroll
            for (int c = 0; c < 4; ++c) acc[c] += bf2f(q[c]);
        }
    }
    unsigned short* o = outi + (size_t)t * FRo + ((size_t)y * PWo + x) * D_ + d4 * 4;
#pragma unroll
    for (int c = 0; c < 4; ++c) o[c] = f2bf(acc[c] * 0.25f);
}

// ---------------- bilinear sampler on padded map (no clamps needed) ----------
__device__ inline float2 bilin2p(const unsigned short* __restrict__ fb, int PW,
                                 float px, float py, int lane) {
    float x0f = floorf(px), y0f = floorf(py);
    float tx = px - x0f, ty = py - y0f;
    int x0 = (int)x0f, y0 = (int)y0f;
    float acc0 = 0.f, acc1 = 0.f;
#pragma unroll
    for (int dy = 0; dy < 2; ++dy) {
#pragma unroll
        for (int dx = 0; dx < 2; ++dx) {
            long xi = x0 + dx, yi = y0 + dy;
            float w = (dx ? tx : 1.f - tx) * (dy ? ty : 1.f - ty);
            unsigned int pk = *(const unsigned int*)(fb + (yi * PW + xi) * D_ + lane * 2);
            acc0 += w * bf2f((unsigned short)(pk & 0xffffu));
            acc1 += w * bf2f((unsigned short)(pk >> 16));
        }
    }
    return {acc0, acc1};
}

// ---------------- track-support features, all levels: (4,N,64,128) bf16 ------
__global__ __launch_bounds__(256) void k_tf(const unsigned short* __restrict__ f0,
                                            const unsigned short* __restrict__ f1,
                                            const unsigned short* __restrict__ f2,
                                            const unsigned short* __restrict__ f3,
                                            const float* __restrict__ qcoords,
                                            const int* __restrict__ qframes,
                                            unsigned short* __restrict__ tfg) {
    int n = blockIdx.x, lvl = blockIdx.y;
    const unsigned short* fmi = lvl == 0 ? f0 : lvl == 1 ? f1 : lvl == 2 ? f2 : f3;
    int Hs = H_ >> lvl, Ws = W_ >> lvl;
    int PW = Ws + 2 * PAD;
    size_t FR = (size_t)(Hs + 2 * PAD) * PW * D_;
    float inv = 1.0f / (float)(1 << lvl);
    int wid = threadIdx.x >> 6, lane = threadIdx.x & 63;
    int fidx = qframes[n];
    float qx = qcoords[n * 2 + 0] * inv, qy = qcoords[n * 2 + 1] * inv;
    const unsigned short* fb = fmi + (size_t)fidx * FR;
    unsigned short* orow = tfg + ((size_t)lvl * N_ + n) * (64 * D_);
    for (int k = wid; k < 64; k += 4) {
        float2 v = {0.f, 0.f};
        if (k < KP) {
            float px = qx + (float)(k / 7 - 3);
            float py = qy + (float)(k % 7 - 3);
            v = bilin2p(fb, PW, px, py, lane);
        }
        unsigned int pk = (unsigned int)f2bf(v.x) | ((unsigned int)f2bf(v.y) << 16);
        *(unsigned int*)(orow + k * D_ + lane * 2) = pk;
    }
}

// ---------------- cf + 49x49 correlation via shared 8x8 patch ---------------
// One block per (n,t,lvl). r5-proven structure (the only change vs r5: Gs is
// bf16 with stride 64 -> LDS total 40960 B exactly -> 4 blocks/CU, was 3).
// All staging pure global_load_lds with pre-swizzled sources (padded fm =>
// no predication). G = P . tf^T via 64 MFMAs, then 4-tap combine ->
// coalesced packed stores. 2 barriers per block.
__global__ __launch_bounds__(256) void k_cfvol(const unsigned short* __restrict__ f0,
                                               const unsigned short* __restrict__ f1,
                                               const unsigned short* __restrict__ f2,
                                               const unsigned short* __restrict__ f3,
                                               const float* __restrict__ coords,
                                               const unsigned short* __restrict__ tfg,
                                               unsigned short* __restrict__ vol) {
    __shared__ unsigned char tfs[16384];
    __shared__ unsigned char Ps[16384];
    __shared__ unsigned short Gs[64 * 64];   // bf16 G, 8 KB
    int n = blockIdx.x, t = blockIdx.y, lvl = blockIdx.z;
    const unsigned short* fmi = lvl == 0 ? f0 : lvl == 1 ? f1 : lvl == 2 ? f2 : f3;
    int Hs = H_ >> lvl, Ws = W_ >> lvl;
    int PW = Ws + 2 * PAD;
    size_t FR = (size_t)(Hs + 2 * PAD) * PW * D_;
    float inv = 1.0f / (float)(1 << lvl);
    int tid = threadIdx.x, wid = tid >> 6, lane = tid & 63;
    int l15 = lane & 15, hi = lane >> 4;

    float cx = coords[((size_t)t * N_ + n) * 2 + 0] * inv;
    float cy = coords[((size_t)t * N_ + n) * 2 + 1] * inv;
    float fx = floorf(cx), fy = floorf(cy);
    float tx = cx - fx, ty = cy - fy;
    long bx = (long)(int)fx - 3, by = (long)(int)fy - 3;
    const unsigned short* fb = fmi + (size_t)t * FR;
    const unsigned short* tfn = tfg + ((size_t)lvl * N_ + n) * (64 * D_);
    // stage tf (16 gload16, 4/wave); LDS linear, source pre-swizzled
#pragma unroll
    for (int i = 0; i < 4; ++i) {
        int rr = wid * 16 + i * 4 + hi;
        int u = l15 ^ (rr & 7);
        GLOAD16(tfn + rr * 128 + u * 8, tfs + (wid * 4 + i) * 1024);
    }
    // stage P: row rr -> pixel (a = rr>>3, b = rr&7)
#pragma unroll
    for (int i = 0; i < 4; ++i) {
        int rr = wid * 16 + i * 4 + hi;
        int u = l15 ^ (rr & 7);
        GLOAD16(fb + ((by + (rr & 7)) * (long)PW + (bx + (rr >> 3))) * D_ + u * 8,
                Ps + (wid * 4 + i) * 1024);
    }
    asm volatile("s_waitcnt vmcnt(0)" ::: "memory");
    __builtin_amdgcn_s_barrier();
    // G = P . tf^T : wave wid computes G rows [wid*16, wid*16+16)
    f32x4 acc[4] = {f32x4{0,0,0,0}, f32x4{0,0,0,0}, f32x4{0,0,0,0}, f32x4{0,0,0,0}};
#pragma unroll
    for (int ks = 0; ks < 4; ++ks) {
        int colb = ks * 64 + hi * 16;
        int arow = wid * 16 + l15;
        bf16x8 a = *(const bf16x8*)(Ps + arow * 256 + (colb ^ ((arow & 7) << 4)));
#pragma unroll
        for (int ln = 0; ln < 4; ++ln) {
            int brow = ln * 16 + l15;
            bf16x8 b = *(const bf16x8*)(tfs + brow * 256 + (colb ^ ((brow & 7) << 4)));
            acc[ln] = __builtin_amdgcn_mfma_f32_16x16x32_bf16(a, b, acc[ln], 0, 0, 0);
        }
    }
#pragma unroll
    for (int ln = 0; ln < 4; ++ln)
#pragma unroll
        for (int r = 0; r < 4; ++r)
            Gs[(wid * 16 + hi * 4 + r) * 64 + ln * 16 + l15] = f2bf(acc[ln][r]);
    __syncthreads();
    // combine: vol[k*64+l] = w00*G[g,l]+w01*G[g+1,l]+w10*G[g+8,l]+w11*G[g+9,l]
    unsigned int* vrow = (unsigned int*)(vol + (((size_t)lvl * T_ + t) * N_ + n) * K2);
    float w00 = (1.f - tx) * (1.f - ty), w01 = (1.f - tx) * ty;
    float w10 = tx * (1.f - ty), w11 = tx * ty;
    int lh = lane >> 5, ll = lane & 31;
#pragma unroll
    for (int it = 0; it < 7; ++it) {
        int k = it * 8 + wid * 2 + lh;
        if (k < KP) {
            int a0 = k / 7, b0 = k - a0 * 7;
            int g = a0 * 8 + b0;
            const unsigned short* gp = &Gs[g * 64 + ll * 2];
            unsigned int u00 = *(const unsigned int*)(gp);
            unsigned int u01 = *(const unsigned int*)(gp + 64);
            unsigned int u10 = *(const unsigned int*)(gp + 8 * 64);
            unsigned int u11 = *(const unsigned int*)(gp + 9 * 64);
            float r0 = w00 * bf2f((unsigned short)u00) + w01 * bf2f((unsigned short)u01)
                     + w10 * bf2f((unsigned short)u10) + w11 * bf2f((unsigned short)u11);
            float r1 = w00 * bf2f((unsigned short)(u00 >> 16)) + w01 * bf2f((unsigned short)(u01 >> 16))
                     + w10 * bf2f((unsigned short)(u10 >> 16)) + w11 * bf2f((unsigned short)(u11 >> 16));
            vrow[k * 32 + ll] = (unsigned int)f2bf(r0) | ((unsigned int)f2bf(r1) << 16);
        }
    }
}

// ---------------- GEMM1: (24576 x K2) @ w1t^T (384 x K2), BM=64 BN=128 -------
// XCD-swizzled grid, bn-fastest within chunk: A-panel sharers co-locate on XCD.
__global__ __launch_bounds__(256) void k_gemm1(const unsigned short* __restrict__ A,
                                               const unsigned short* __restrict__ Bt,
                                               const float* __restrict__ b1,
                                               unsigned short* __restrict__ Hout) {
    __shared__ unsigned char As[8192];    // 64 rows x 128B, swizzled content
    __shared__ unsigned char Bs[16384];   // 128 rows x 128B
    int bid = blockIdx.x;                           // nwg = 1152 = 8 * 144
    int swz = (bid & 7) * 144 + (bid >> 3);
    int bm = swz / 3, bn = swz % 3;
    int tid = threadIdx.x, lane = tid & 63;
    int wid = tid >> 6, wm = wid & 1, wn = wid >> 1;
    int l15 = lane & 15, hi = lane >> 4;
    f32x4 acc[2][4] = {};
    const unsigned short* Abase = A + (size_t)(bm * 64) * K2;
    const unsigned short* Bbase = Bt + (size_t)(bn * 128) * K2;
    for (int kt = 0; kt < K2 / 64; ++kt) {
#pragma unroll
        for (int q = 0; q < 2; ++q) {
            int e = (wid * 2 + q) * 64 + lane;
            int row = e >> 3, su = (e & 7) ^ (row & 7);
            GLOAD16(Abase + (size_t)row * K2 + kt * 64 + su * 8, As + (wid * 2 + q) * 1024);
        }
#pragma unroll
        for (int q = 0; q < 4; ++q) {
            int e = (wid * 4 + q) * 64 + lane;
            int row = e >> 3, su = (e & 7) ^ (row & 7);
            GLOAD16(Bbase + (size_t)row * K2 + kt * 64 + su * 8, Bs + (wid * 4 + q) * 1024);
        }
        __syncthreads();
#pragma unroll
        for (int ks = 0; ks < 2; ++ks) {
            int colb = ks * 64 + hi * 16;
            bf16x8 a[2], b[4];
#pragma unroll
            for (int km = 0; km < 2; ++km) {
                int arow = wm * 32 + km * 16 + l15;
                a[km] = *(const bf16x8*)(As + arow * 128 + (colb ^ ((arow & 7) << 4)));
            }
#pragma unroll
            for (int ln = 0; ln < 4; ++ln) {
                int brow = wn * 64 + ln * 16 + l15;
                b[ln] = *(const bf16x8*)(Bs + brow * 128 + (colb ^ ((brow & 7) << 4)));
            }
#pragma unroll
            for (int km = 0; km < 2; ++km)
#pragma unroll
                for (int ln = 0; ln < 4; ++ln)
                    acc[km][ln] = __builtin_amdgcn_mfma_f32_16x16x32_bf16(a[km], b[ln], acc[km][ln], 0, 0, 0);
        }
        __syncthreads();
    }
#pragma unroll
    for (int km = 0; km < 2; ++km)
#pragma unroll
        for (int ln = 0; ln < 4; ++ln)
#pragma unroll
            for (int r = 0; r < 4; ++r) {
                int row = bm * 64 + wm * 32 + km * 16 + hi * 4 + r;
                int col = bn * 128 + wn * 64 + ln * 16 + l15;
                float x = acc[km][ln][r] + b1[col];
                float g = 0.5f * x * (1.f + erff(x * 0.70710678118654752f));
                Hout[(size_t)row * H1 + col] = f2bf(g);
            }
}

// ---------------- GEMM2: (24576 x 384) @ w2t^T (256 x 384), BM=64 BN=128 -----
__global__ __launch_bounds__(256) void k_gemm2(const unsigned short* __restrict__ A,
                                               const unsigned short* __restrict__ Bt,
                                               const float* __restrict__ b2,
                                               float* __restrict__ outp) {
    __shared__ unsigned char As[8192];    // 64 x 128B
    __shared__ unsigned char Bs[16384];   // 128 x 128B
    int bid = blockIdx.x;                           // nwg = 768 = 8 * 96
    int swz = (bid & 7) * 96 + (bid >> 3);
    int bm = swz >> 1, bn = swz & 1;
    int tid = threadIdx.x, lane = tid & 63;
    int wid = tid >> 6, wm = wid & 1, wn = wid >> 1;
    int l15 = lane & 15, hi = lane >> 4;
    f32x4 acc[2][4] = {};
    const unsigned short* Abase = A + (size_t)(bm * 64) * H1;
    const unsigned short* Bbase = Bt + (size_t)(bn * 128) * H1;
    for (int kt = 0; kt < H1 / 64; ++kt) {
#pragma unroll
        for (int q = 0; q < 2; ++q) {
            int e = (wid * 2 + q) * 64 + lane;
            int row = e >> 3, su = (e & 7) ^ (row & 7);
            GLOAD16(Abase + (size_t)row * H1 + kt * 64 + su * 8, As + (wid * 2 + q) * 1024);
        }
#pragma unroll
        for (int q = 0; q < 4; ++q) {
            int e = (wid * 4 + q) * 64 + lane;
            int row = e >> 3, su = (e & 7) ^ (row & 7);
            GLOAD16(Bbase + (size_t)row * H1 + kt * 64 + su * 8, Bs + (wid * 4 + q) * 1024);
        }
        __syncthreads();
#pragma unroll
        for (int ks = 0; ks < 2; ++ks) {
            int colb = ks * 64 + hi * 16;
            bf16x8 a[2], b[4];
#pragma unroll
            for (int km = 0; km < 2; ++km) {
                int arow = wm * 32 + km * 16 + l15;
                a[km] = *(const bf16x8*)(As + arow * 128 + (colb ^ ((arow & 7) << 4)));
            }
#pragma unroll
            for (int ln = 0; ln < 4; ++ln) {
                int brow = wn * 64 + ln * 16 + l15;
                b[ln] = *(const bf16x8*)(Bs + brow * 128 + (colb ^ ((brow & 7) << 4)));
            }
#pragma unroll
            for (int km = 0; km < 2; ++km)
#pragma unroll
                for (int ln = 0; ln < 4; ++ln)
                    acc[km][ln] = __builtin_amdgcn_mfma_f32_16x16x32_bf16(a[km], b[ln], acc[km][ln], 0, 0, 0);
        }
        __syncthreads();
    }
#pragma unroll
    for (int km = 0; km < 2; ++km)
#pragma unroll
        for (int ln = 0; ln < 4; ++ln)
#pragma unroll
            for (int r = 0; r < 4; ++r) {
                int row = bm * 64 + wm * 32 + km * 16 + hi * 4 + r;
                int col = bn * 128 + wn * 64 + ln * 16 + l15;
                int lvl = row / (T_ * N_);
                int r2 = row - lvl * (T_ * N_);
                outp[(size_t)r2 * (4 * OUTC) + lvl * OUTC + col] = acc[km][ln][r] + b2[col];
            }
}

extern "C" void kernel_launch(void* const* d_in, const int* in_sizes, int n_in,
                              void* d_out, int out_size, void* d_ws, size_t ws_size,
                              hipStream_t stream) {
    const float* fmaps   = (const float*)d_in[0];
    const float* coords  = (const float*)d_in[1];
    const float* qcoords = (const float*)d_in[2];
    const int*   qframes = (const int*)d_in[3];
    const float* w1      = (const float*)d_in[4];
    const float* b1      = (const float*)d_in[5];
    const float* w2      = (const float*)d_in[6];
    const float* b2      = (const float*)d_in[7];
    float* outp = (float*)d_out;

    unsigned char* ws = (unsigned char*)d_ws;
    size_t off = 0;
    auto take = [&](size_t bytes) {
        unsigned char* p = ws + off;
        off += (bytes + 255) & ~(size_t)255;
        return p;
    };
    // padded pyramid buffers
    const int Hs[4] = {96, 48, 24, 12}, Wss[4] = {128, 64, 32, 16};
    unsigned short* fmraw[4];
    unsigned short* fmint[4];
    for (int l = 0; l < 4; ++l) {
        int PH = Hs[l] + 2 * PAD, PW = Wss[l] + 2 * PAD;
        fmraw[l] = (unsigned short*)take((size_t)T_ * PH * PW * D_ * 2);
        fmint[l] = fmraw[l] + ((size_t)PAD * PW + PAD) * D_;
    }
    unsigned short* tfg  = (unsigned short*)take((size_t)4 * N_ * 64 * D_ * 2);
    unsigned short* vol  = (unsigned short*)take((size_t)MTOT * K2 * 2);
    unsigned short* hbuf = (unsigned short*)take((size_t)MTOT * H1 * 2);
    unsigned short* w1t  = (unsigned short*)take((size_t)H1 * K2 * 2);
    unsigned short* w2t  = (unsigned short*)take((size_t)OUTC * H1 * 2);

    for (int l = 0; l < 4; ++l)
        hipLaunchKernelGGL(k_padzero, dim3(4096), dim3(256), 0, stream,
                           (uint4*)fmraw[l], Hs[l], Wss[l]);
    hipLaunchKernelGGL(k_w1t, dim3((H1 * K2 + 255) / 256), dim3(256), 0, stream, w1, w1t);
    hipLaunchKernelGGL(k_w2t, dim3((OUTC * H1 + 255) / 256), dim3(256), 0, stream, w2, w2t);
    hipLaunchKernelGGL(k_normalize, dim3(T_ * H_), dim3(256), 0, stream, fmaps, fmint[0]);
    hipLaunchKernelGGL(k_pool, dim3((T_ * 48 * 64 * 32 + 255) / 256), dim3(256), 0, stream,
                       fmint[0], fmint[1], 96, 128);
    hipLaunchKernelGGL(k_pool, dim3((T_ * 24 * 32 * 32 + 255) / 256), dim3(256), 0, stream,
                       fmint[1], fmint[2], 48, 64);
    hipLaunchKernelGGL(k_pool, dim3((T_ * 12 * 16 * 32 + 255) / 256), dim3(256), 0, stream,
                       fmint[2], fmint[3], 24, 32);

    hipLaunchKernelGGL(k_tf, dim3(N_, 4), dim3(256), 0, stream,
                       fmint[0], fmint[1], fmint[2], fmint[3], qcoords, qframes, tfg);
    hipLaunchKernelGGL(k_cfvol, dim3(N_, T_, 4), dim3(256), 0, stream,
                       fmint[0], fmint[1], fmint[2], fmint[3], coords, tfg, vol);
    hipLaunchKernelGGL(k_gemm1, dim3(384 * 3), dim3(256), 0, stream, vol, w1t, b1, hbuf);
    hipLaunchKernelGGL(k_gemm2, dim3(384 * 2), dim3(256), 0, stream, hbuf, w2t, b2, outp);
}